// Round 4
// baseline (1702.975 us; speedup 1.0000x reference)
//
#include <hip/hip_runtime.h>

// Problem constants (B=4, L=2048, D=512, H=8, DK=64, FF=2048, U=40)
#define BB 4
#define LL 2048
#define DD 512
#define HH 8
#define DKK 64
#define FF 2048

// ---------------- weight transpose: dst[n*512+k] = src[k*512+n], 4 mats ----
__global__ __launch_bounds__(256) void transpose_w(
    const float* __restrict__ s0, const float* __restrict__ s1,
    const float* __restrict__ s2, const float* __restrict__ s3,
    float* __restrict__ d)
{
    const float* s = (blockIdx.z == 0) ? s0 : (blockIdx.z == 1) ? s1
                     : (blockIdx.z == 2) ? s2 : s3;
    float* dd = d + (size_t)blockIdx.z * DD * DD;
    int idx = blockIdx.x * 256 + threadIdx.x;     // 0 .. 512*512-1
    int k = idx >> 9, n = idx & 511;
    dd[(size_t)n * DD + k] = s[idx];
}

// ---------------- generic GEMM  C[M,N] = act(A[M,K] @ B[N,K]^T + bias) -----
// all fp32. ACT: 0=none 1=gelu(exact, erf-based).
template<int ACT, bool BIAS>
__global__ __launch_bounds__(256) void gemm_nt(
    const float* __restrict__ A, const float* __restrict__ B,
    const float* __restrict__ bias, float* __restrict__ C,
    int M, int N, int K)
{
    constexpr int TK = 32;
    __shared__ float As[64][TK + 1];
    __shared__ float Bs[64][TK + 1];
    const int tid = threadIdx.x;
    const int tx = tid & 15, ty = tid >> 4;
    const int m0 = blockIdx.y * 64, n0 = blockIdx.x * 64;
    const int lrow = tid >> 2;          // 0..63
    const int lcol = (tid & 3) * 8;     // 0,8,16,24

    float acc[4][4] = {};
    for (int k0 = 0; k0 < K; k0 += TK) {
        float4 a0 = *reinterpret_cast<const float4*>(A + (size_t)(m0 + lrow) * K + k0 + lcol);
        float4 a1 = *reinterpret_cast<const float4*>(A + (size_t)(m0 + lrow) * K + k0 + lcol + 4);
        float4 b0 = *reinterpret_cast<const float4*>(B + (size_t)(n0 + lrow) * K + k0 + lcol);
        float4 b1 = *reinterpret_cast<const float4*>(B + (size_t)(n0 + lrow) * K + k0 + lcol + 4);
        As[lrow][lcol + 0] = a0.x; As[lrow][lcol + 1] = a0.y;
        As[lrow][lcol + 2] = a0.z; As[lrow][lcol + 3] = a0.w;
        As[lrow][lcol + 4] = a1.x; As[lrow][lcol + 5] = a1.y;
        As[lrow][lcol + 6] = a1.z; As[lrow][lcol + 7] = a1.w;
        Bs[lrow][lcol + 0] = b0.x; Bs[lrow][lcol + 1] = b0.y;
        Bs[lrow][lcol + 2] = b0.z; Bs[lrow][lcol + 3] = b0.w;
        Bs[lrow][lcol + 4] = b1.x; Bs[lrow][lcol + 5] = b1.y;
        Bs[lrow][lcol + 6] = b1.z; Bs[lrow][lcol + 7] = b1.w;
        __syncthreads();
        #pragma unroll
        for (int kk = 0; kk < TK; kk++) {
            float a[4], b[4];
            #pragma unroll
            for (int i = 0; i < 4; i++) a[i] = As[ty * 4 + i][kk];
            #pragma unroll
            for (int j = 0; j < 4; j++) b[j] = Bs[tx * 4 + j][kk];
            #pragma unroll
            for (int i = 0; i < 4; i++)
                #pragma unroll
                for (int j = 0; j < 4; j++) acc[i][j] += a[i] * b[j];
        }
        __syncthreads();
    }
    #pragma unroll
    for (int i = 0; i < 4; i++) {
        int m = m0 + ty * 4 + i;
        #pragma unroll
        for (int j = 0; j < 4; j++) {
            int n = n0 + tx * 4 + j;
            float v = acc[i][j];
            if (BIAS) v += bias[n];
            if (ACT == 1) v = 0.5f * v * (1.0f + erff(v * 0.70710678118654752f));
            C[(size_t)m * N + n] = v;
        }
    }
}

// ------------- M[b,h,l] = max_s(q·k_s) - sum_s(q·k_s)/L  (sampled) ---------
__global__ __launch_bounds__(256) void calc_m(
    const float* __restrict__ Q, const float* __restrict__ Kb,
    const int* __restrict__ sidx, float* __restrict__ Mo, int U)
{
    int gid = blockIdx.x * 256 + threadIdx.x;   // b*H*L + h*L + l
    if (gid >= BB * HH * LL) return;
    int l = gid & (LL - 1);
    int h = (gid >> 11) & (HH - 1);
    int b = gid >> 14;
    const float* qr = Q + ((size_t)(b * LL + l) * DD + h * DKK);
    float q[DKK];
    #pragma unroll
    for (int d = 0; d < DKK; d++) q[d] = qr[d];
    float mx = -1e30f, sm = 0.f;
    for (int s = 0; s < U; s++) {
        int j = sidx[l * U + s];
        const float* kr = Kb + ((size_t)(b * LL + j) * DD + h * DKK);
        float dot = 0.f;
        #pragma unroll
        for (int d = 0; d < DKK; d++) dot += q[d] * kr[d];
        mx = fmaxf(mx, dot); sm += dot;
    }
    Mo[gid] = mx - sm * (1.0f / (float)LL);
}

// ------------- iterative top-40 per (b,h) row of M -------------------------
__global__ __launch_bounds__(256) void topk_k(
    const float* __restrict__ Mo, int* __restrict__ top, int U)
{
    __shared__ float sv[LL];
    __shared__ float rv[256];
    __shared__ int   ri[256];
    int bh = blockIdx.x, tid = threadIdx.x;
    for (int i = tid; i < LL; i += 256) sv[i] = Mo[(size_t)bh * LL + i];
    __syncthreads();
    for (int it = 0; it < U; it++) {
        float best = -1e38f; int bi = LL - 1;
        for (int i = tid; i < LL; i += 256) {
            float v = sv[i];
            if (v > best) { best = v; bi = i; }
        }
        rv[tid] = best; ri[tid] = bi; __syncthreads();
        for (int s = 128; s > 0; s >>= 1) {
            if (tid < s) {
                float vo = rv[tid + s]; int io = ri[tid + s];
                if (vo > rv[tid] || (vo == rv[tid] && io < ri[tid])) { rv[tid] = vo; ri[tid] = io; }
            }
            __syncthreads();
        }
        if (tid == 0) { top[bh * U + it] = ri[0]; sv[ri[0]] = -1e38f; }
        __syncthreads();
    }
}

// ------------- Vmean[b,h,d] ------------------------------------------------
__global__ __launch_bounds__(64) void vmean_k(
    const float* __restrict__ V, float* __restrict__ Vm)
{
    int bh = blockIdx.x, d = threadIdx.x;
    int b = bh >> 3, h = bh & 7;
    const float* vp = V + ((size_t)b * LL * DD + h * DKK + d);
    float s = 0.f;
    for (int l = 0; l < LL; l++) s += vp[(size_t)l * DD];
    Vm[bh * DKK + d] = s * (1.0f / (float)LL);
}

// ------------- fused: upd[row,:] = softmax(Q[top]·K^T/8) @ V ---------------
__global__ __launch_bounds__(256) void attn_fused(
    const float* __restrict__ Q, const float* __restrict__ Kb,
    const float* __restrict__ V, const int* __restrict__ top,
    float* __restrict__ upd, int U)
{
    __shared__ float qs[DKK];
    __shared__ float p[LL];
    __shared__ float red[256];
    __shared__ float osum[4][DKK];
    int row = blockIdx.x;              // bh*U + u
    int u = row % U, bh = row / U;
    int h = bh & 7, b = bh >> 3;
    int tid = threadIdx.x;
    int tq = top[bh * U + u];
    if (tid < DKK) qs[tid] = Q[((size_t)(b * LL + tq) * DD + h * DKK) + tid];
    __syncthreads();
    float sc[8]; float mx = -1e30f;
    #pragma unroll
    for (int i = 0; i < 8; i++) {
        int l = tid + i * 256;
        const float4* kr = (const float4*)(Kb + ((size_t)(b * LL + l) * DD + h * DKK));
        float dot = 0.f;
        #pragma unroll
        for (int d4 = 0; d4 < 16; d4++) {
            float4 kv = kr[d4];
            dot += qs[d4 * 4 + 0] * kv.x + qs[d4 * 4 + 1] * kv.y
                 + qs[d4 * 4 + 2] * kv.z + qs[d4 * 4 + 3] * kv.w;
        }
        sc[i] = dot * 0.125f;
        mx = fmaxf(mx, sc[i]);
    }
    red[tid] = mx; __syncthreads();
    for (int s = 128; s > 0; s >>= 1) { if (tid < s) red[tid] = fmaxf(red[tid], red[tid + s]); __syncthreads(); }
    mx = red[0]; __syncthreads();
    float se = 0.f;
    #pragma unroll
    for (int i = 0; i < 8; i++) { sc[i] = __expf(sc[i] - mx); se += sc[i]; }
    red[tid] = se; __syncthreads();
    for (int s = 128; s > 0; s >>= 1) { if (tid < s) red[tid] += red[tid + s]; __syncthreads(); }
    float inv = 1.0f / red[0];
    #pragma unroll
    for (int i = 0; i < 8; i++) p[tid + i * 256] = sc[i] * inv;
    __syncthreads();
    // phase 2: upd[d] = sum_l p[l] * V[b,h,l,d]; 4 l-chunks of 512 in parallel
    int d = tid & 63, part = tid >> 6;
    const float* vp = V + ((size_t)b * LL * DD + h * DKK + d);
    float acc = 0.f;
    int l0 = part * 512;
    for (int l = l0; l < l0 + 512; l++) acc += p[l] * vp[(size_t)l * DD];
    osum[part][d] = acc;
    __syncthreads();
    if (tid < DKK)
        upd[(size_t)row * DKK + tid] = osum[0][tid] + osum[1][tid] + osum[2][tid] + osum[3][tid];
}

// ------------- ctx init (broadcast Vmean) + scatter ------------------------
__global__ __launch_bounds__(256) void ctx_init(
    const float* __restrict__ Vm, float* __restrict__ ctx)
{
    int idx = blockIdx.x * 256 + threadIdx.x;   // over B*L*512
    int c = idx & 511; int h = c >> 6, d = c & 63;
    int bl = idx >> 9; int b = bl >> 11;
    ctx[idx] = Vm[(b * HH + h) * DKK + d];
}
__global__ __launch_bounds__(256) void ctx_scatter(
    const float* __restrict__ upd, const int* __restrict__ top,
    float* __restrict__ ctx, int U, int total)
{
    int idx = blockIdx.x * 256 + threadIdx.x;   // bh*U*64
    if (idx >= total) return;
    int d = idx & 63; int ru = idx >> 6;        // bh*U+u
    int bh = ru / U, u = ru % U;
    int b = bh >> 3, h = bh & 7;
    int l = top[bh * U + u];
    ctx[(((size_t)(b * LL + l)) << 9) + h * DKK + d] = upd[idx];
}

// ------------- LN1: x1 = LN(x + aout) --------------------------------------
__global__ __launch_bounds__(256) void ln1_k(
    const float* __restrict__ x, const float* __restrict__ aout,
    const float* __restrict__ g, const float* __restrict__ bb,
    float* __restrict__ x1)
{
    __shared__ float red[256];
    int row = blockIdx.x, tid = threadIdx.x;
    size_t base = (size_t)row * DD;
    float h0 = x[base + tid] + aout[base + tid];
    float h1 = x[base + 256 + tid] + aout[base + 256 + tid];
    red[tid] = h0 + h1; __syncthreads();
    for (int s = 128; s > 0; s >>= 1) { if (tid < s) red[tid] += red[tid + s]; __syncthreads(); }
    float mean = red[0] * (1.0f / DD); __syncthreads();
    float d0 = h0 - mean, d1 = h1 - mean;
    red[tid] = d0 * d0 + d1 * d1; __syncthreads();
    for (int s = 128; s > 0; s >>= 1) { if (tid < s) red[tid] += red[tid + s]; __syncthreads(); }
    float rstd = rsqrtf(red[0] * (1.0f / DD) + 1e-5f);
    x1[base + tid]       = d0 * rstd * g[tid] + bb[tid];
    x1[base + 256 + tid] = d1 * rstd * g[256 + tid] + bb[256 + tid];
}

// ------------- LN2: out = LN(x1 + ffn2 + b2) -------------------------------
__global__ __launch_bounds__(256) void ln2_k(
    const float* __restrict__ x1, const float* __restrict__ f2o,
    const float* __restrict__ c2b,
    const float* __restrict__ g, const float* __restrict__ bb,
    float* __restrict__ out)
{
    __shared__ float red[256];
    int row = blockIdx.x, tid = threadIdx.x;
    size_t base = (size_t)row * DD;
    float h0 = x1[base + tid] + f2o[base + tid] + c2b[tid];
    float h1 = x1[base + 256 + tid] + f2o[base + 256 + tid] + c2b[256 + tid];
    red[tid] = h0 + h1; __syncthreads();
    for (int s = 128; s > 0; s >>= 1) { if (tid < s) red[tid] += red[tid + s]; __syncthreads(); }
    float mean = red[0] * (1.0f / DD); __syncthreads();
    float d0 = h0 - mean, d1 = h1 - mean;
    red[tid] = d0 * d0 + d1 * d1; __syncthreads();
    for (int s = 128; s > 0; s >>= 1) { if (tid < s) red[tid] += red[tid + s]; __syncthreads(); }
    float rstd = rsqrtf(red[0] * (1.0f / DD) + 1e-5f);
    out[base + tid]       = d0 * rstd * g[tid] + bb[tid];
    out[base + 256 + tid] = d1 * rstd * g[256 + tid] + bb[256 + tid];
}

// ---------------------------------------------------------------------------
extern "C" void kernel_launch(void* const* d_in, const int* in_sizes, int n_in,
                              void* d_out, int out_size, void* d_ws, size_t ws_size,
                              hipStream_t stream)
{
    const float* x   = (const float*)d_in[0];
    const float* Wq  = (const float*)d_in[1];
    const float* Wk  = (const float*)d_in[2];
    const float* Wv  = (const float*)d_in[3];
    const float* Wo  = (const float*)d_in[4];
    const float* g1  = (const float*)d_in[5];
    const float* b1  = (const float*)d_in[6];
    const float* c1w = (const float*)d_in[7];
    const float* c1b = (const float*)d_in[8];
    const float* c2w = (const float*)d_in[9];
    const float* c2b = (const float*)d_in[10];
    const float* g2  = (const float*)d_in[11];
    const float* b2  = (const float*)d_in[12];
    const int* sidx  = (const int*)d_in[13];
    float* out       = (float*)d_out;

    const int U = in_sizes[13] / LL;            // 40
    const int M = BB * LL;                       // 8192

    // ---- workspace layout (~52.6 MB peak), lifetime-safe aliasing ----
    // [0,16M)   : Q fp32   -> aout (after attn) -> f2o (after ln1)
    // [16,32M)  : K fp32   -> x1   (after attn)
    // [32,48M)  : V fp32   -> ctx  (after attn) -> ych FFN chunk (after out-proj)
    // [48,52M)  : WT fp32 (4 x 512x512 transposed)
    // [52M+..)  : Mo (256K), upd (320K), Vm (8K), top (5K)
    char* ws = (char*)d_ws;
    const size_t MB = (size_t)1 << 20;
    float* Q    = (float*)(ws + 0);
    float* Kb   = (float*)(ws + 16 * MB);
    float* V    = (float*)(ws + 32 * MB);
    float* WT   = (float*)(ws + 48 * MB);
    float* Mo   = (float*)(ws + 52 * MB);
    float* upd  = (float*)(ws + 52 * MB + 256 * 1024);
    float* Vm   = (float*)(ws + 52 * MB + 576 * 1024);
    int*   top  = (int*)  (ws + 52 * MB + 584 * 1024);
    float* aout = Q;            // alias: Q dead after attn_fused
    float* f2o  = Q;            // alias: aout dead after ln1
    float* x1   = Kb;           // alias: K dead after attn_fused
    float* ctx  = V;            // alias: V dead after attn_fused
    float* ych  = V;            // alias: ctx dead after out-proj
    (void)ws_size; (void)n_in; (void)out_size;

    float* WqT = WT;
    float* WkT = WT + (size_t)DD * DD;
    float* WvT = WT + (size_t)2 * DD * DD;
    float* WoT = WT + (size_t)3 * DD * DD;

    // 1) transpose the four 512x512 weights -> (N,K) form
    transpose_w<<<dim3(DD * DD / 256, 1, 4), 256, 0, stream>>>(Wq, Wk, Wv, Wo, WT);

    // 2) Q,K,V projections
    dim3 gqkv(DD / 64, M / 64);
    gemm_nt<0, false><<<gqkv, 256, 0, stream>>>(x, WqT, nullptr, Q,  M, DD, DD);
    gemm_nt<0, false><<<gqkv, 256, 0, stream>>>(x, WkT, nullptr, Kb, M, DD, DD);
    gemm_nt<0, false><<<gqkv, 256, 0, stream>>>(x, WvT, nullptr, V,  M, DD, DD);

    // 3) sampled sparsity measure M, top-k, V mean
    calc_m<<<BB * HH * LL / 256, 256, 0, stream>>>(Q, Kb, sidx, Mo, U);
    topk_k<<<BB * HH, 256, 0, stream>>>(Mo, top, U);
    vmean_k<<<BB * HH, 64, 0, stream>>>(V, Vm);

    // 4) fused sparse attention: softmax(Q_red K^T / 8) @ V -> upd (Q,K,V die here)
    attn_fused<<<BB * HH * U, 256, 0, stream>>>(Q, Kb, V, top, upd, U);

    // 5) context assembly (ctx aliases V) + out-projection (aout aliases Q)
    ctx_init<<<M * DD / 256, 256, 0, stream>>>(Vm, ctx);
    int sc_total = BB * HH * U * DKK;
    ctx_scatter<<<(sc_total + 255) / 256, 256, 0, stream>>>(upd, top, ctx, U, sc_total);
    gemm_nt<0, false><<<gqkv, 256, 0, stream>>>(ctx, WoT, nullptr, aout, M, DD, DD);

    // 6) LN1 -> x1 (aliases K)
    ln1_k<<<M, 256, 0, stream>>>(x, aout, g1, b1, x1);

    // 7) FFN in 4 chunks of 2048 rows; ych (16MB) aliases ctx (dead).
    //    conv weights are already (N,K) -> gemm_nt directly, no transpose.
    //    f2o aliases aout (dead after ln1). bias2 added in LN2.
    for (int c = 0; c < 4; c++) {
        const float* x1c = x1 + (size_t)c * 2048 * DD;
        float* f2oc = f2o + (size_t)c * 2048 * DD;
        gemm_nt<1, true ><<<dim3(FF / 64, 2048 / 64), 256, 0, stream>>>(x1c, c1w, c1b, ych, 2048, FF, DD);
        gemm_nt<0, false><<<dim3(DD / 64, 2048 / 64), 256, 0, stream>>>(ych, c2w, nullptr, f2oc, 2048, DD, FF);
    }

    // 8) LN2 -> fp32 output
    ln2_k<<<M, 256, 0, stream>>>(x1, f2o, c2b, g2, b2, out);
}

// Round 5
// 649.075 us; speedup vs baseline: 2.6237x; 2.6237x over previous
//
#include <hip/hip_runtime.h>
#include <hip/hip_bf16.h>

// Problem constants (B=4, L=2048, D=512, H=8, DK=64, FF=2048, U=40)
#define BB 4
#define LL 2048
#define DD 512
#define HH 8
#define DKK 64
#define FF 2048

typedef __bf16  bf16x8  __attribute__((ext_vector_type(8)));
typedef float   floatx4 __attribute__((ext_vector_type(4)));

// async 16B global->LDS copy (global_load_lds_dwordx4)
__device__ __forceinline__ void async_cp16(const void* g, void* l) {
    __builtin_amdgcn_global_load_lds(
        (const __attribute__((address_space(1))) unsigned int*)g,
        (__attribute__((address_space(3))) unsigned int*)l,
        16, 0, 0);
}

// ---------- prep: transpose 512x512 fp32 -> bf16 (N,K); Wq/Wk also lo-part ----
__global__ __launch_bounds__(256) void prep_w(
    const float* __restrict__ Wq, const float* __restrict__ Wk,
    const float* __restrict__ Wv, const float* __restrict__ Wo,
    __bf16* __restrict__ wb)
{
    const size_t SZ = (size_t)DD * DD;
    int z = blockIdx.z;
    const float* s = (z == 0) ? Wq : (z == 1) ? Wk : (z == 2) ? Wv : Wo;
    __bf16* hi; __bf16* lo = nullptr;
    if (z == 0)      { hi = wb;          lo = wb + SZ; }
    else if (z == 1) { hi = wb + 2 * SZ; lo = wb + 3 * SZ; }
    else if (z == 2) { hi = wb + 4 * SZ; }
    else             { hi = wb + 5 * SZ; }
    int idx = blockIdx.x * 256 + threadIdx.x;   // 0..512*512-1
    int k = idx >> 9, n = idx & 511;
    float v = s[idx];
    __bf16 h = (__bf16)v;
    hi[(size_t)n * DD + k] = h;
    if (lo) lo[(size_t)n * DD + k] = (__bf16)(v - (float)h);
}

// ---------- cast conv weights fp32 (N,K) -> bf16 -----------------------------
__global__ __launch_bounds__(256) void cast_cw(
    const float* __restrict__ c1w, const float* __restrict__ c2w,
    __bf16* __restrict__ d1, __bf16* __restrict__ d2)
{
    const float* s = blockIdx.z ? c2w : c1w;
    __bf16* d = blockIdx.z ? d2 : d1;
    int idx = blockIdx.x * 256 + threadIdx.x;   // 0..FF*DD-1
    d[idx] = (__bf16)s[idx];
}

// ---------- split-cast x fp32 -> bf16 hi + lo --------------------------------
__global__ __launch_bounds__(256) void split_cast_x(
    const float* __restrict__ x, __bf16* __restrict__ xhi, __bf16* __restrict__ xlo)
{
    int idx = blockIdx.x * 256 + threadIdx.x;
    float v = x[idx];
    __bf16 h = (__bf16)v;
    xhi[idx] = h;
    xlo[idx] = (__bf16)(v - (float)h);
}

// ---------- MFMA GEMM: C[M,N] = act(A[M,K] @ B[N,K]^T + bias) ----------------
// A,B bf16 row-major along K. 128x128 tile, BK=32, 4 waves, 4x4 16x16 MFMA/wave.
template<int ACT, bool BIAS, bool OUT_BF16>
__global__ __launch_bounds__(256) void gemm_mfma(
    const __bf16* __restrict__ A, const __bf16* __restrict__ B,
    const float* __restrict__ bias, void* __restrict__ Cv,
    int M, int N, int K)
{
    __shared__ __bf16 As[128 * 32];
    __shared__ __bf16 Bs[128 * 32];
    const int tid = threadIdx.x;
    const int wave = tid >> 6, lane = tid & 63;
    const int m0 = blockIdx.y * 128, n0 = blockIdx.x * 128;
    const int wm = (wave >> 1) * 64, wn = (wave & 1) * 64;
    const int l15 = lane & 15, kq = lane >> 4;

    floatx4 acc[4][4] = {};

    for (int k0 = 0; k0 < K; k0 += 32) {
        #pragma unroll
        for (int p = 0; p < 2; p++) {
            int c = p * 256 + tid;              // 16B chunk id 0..511
            int row = c >> 2, col = (c & 3) * 8;
            async_cp16(A + (size_t)(m0 + row) * K + k0 + col, As + c * 8);
            async_cp16(B + (size_t)(n0 + row) * K + k0 + col, Bs + c * 8);
        }
        __syncthreads();
        bf16x8 af[4], bfr[4];
        #pragma unroll
        for (int i = 0; i < 4; i++)
            af[i] = *(const bf16x8*)(As + (wm + i * 16 + l15) * 32 + kq * 8);
        #pragma unroll
        for (int j = 0; j < 4; j++)
            bfr[j] = *(const bf16x8*)(Bs + (wn + j * 16 + l15) * 32 + kq * 8);
        #pragma unroll
        for (int i = 0; i < 4; i++)
            #pragma unroll
            for (int j = 0; j < 4; j++)
                acc[i][j] = __builtin_amdgcn_mfma_f32_16x16x32_bf16(af[i], bfr[j], acc[i][j], 0, 0, 0);
        __syncthreads();
    }
    // epilogue: C[row=(lane>>4)*4+r][col=lane&15] per 16x16 tile
    #pragma unroll
    for (int i = 0; i < 4; i++) {
        #pragma unroll
        for (int j = 0; j < 4; j++) {
            int col = n0 + wn + j * 16 + l15;
            float bv = BIAS ? bias[col] : 0.0f;
            #pragma unroll
            for (int r = 0; r < 4; r++) {
                int row = m0 + wm + i * 16 + kq * 4 + r;
                float v = acc[i][j][r] + bv;
                if (ACT == 1) v = 0.5f * v * (1.0f + erff(v * 0.70710678118654752f));
                if (OUT_BF16) ((__bf16*)Cv)[(size_t)row * N + col] = (__bf16)v;
                else          ((float*)Cv)[(size_t)row * N + col] = v;
            }
        }
    }
}

// ---------- split-precision MFMA GEMM (near-fp32): C = (Ah+Al)(Bh+Bl)^T ------
// Drops Al*Bl term; 3 MFMAs per tile. fp32 output, no bias/act.
__global__ __launch_bounds__(256) void gemm_mfma_split(
    const __bf16* __restrict__ Ah, const __bf16* __restrict__ Al,
    const __bf16* __restrict__ Bh, const __bf16* __restrict__ Bl,
    float* __restrict__ C, int M, int N, int K)
{
    __shared__ __bf16 Ahs[128 * 32];
    __shared__ __bf16 Als[128 * 32];
    __shared__ __bf16 Bhs[128 * 32];
    __shared__ __bf16 Bls[128 * 32];
    const int tid = threadIdx.x;
    const int wave = tid >> 6, lane = tid & 63;
    const int m0 = blockIdx.y * 128, n0 = blockIdx.x * 128;
    const int wm = (wave >> 1) * 64, wn = (wave & 1) * 64;
    const int l15 = lane & 15, kq = lane >> 4;

    floatx4 acc[4][4] = {};

    for (int k0 = 0; k0 < K; k0 += 32) {
        #pragma unroll
        for (int p = 0; p < 2; p++) {
            int c = p * 256 + tid;
            int row = c >> 2, col = (c & 3) * 8;
            size_t goA = (size_t)(m0 + row) * K + k0 + col;
            size_t goB = (size_t)(n0 + row) * K + k0 + col;
            async_cp16(Ah + goA, Ahs + c * 8);
            async_cp16(Al + goA, Als + c * 8);
            async_cp16(Bh + goB, Bhs + c * 8);
            async_cp16(Bl + goB, Bls + c * 8);
        }
        __syncthreads();
        bf16x8 ah[4], al[4], bh[4], bl[4];
        #pragma unroll
        for (int i = 0; i < 4; i++) {
            int off = (wm + i * 16 + l15) * 32 + kq * 8;
            ah[i] = *(const bf16x8*)(Ahs + off);
            al[i] = *(const bf16x8*)(Als + off);
        }
        #pragma unroll
        for (int j = 0; j < 4; j++) {
            int off = (wn + j * 16 + l15) * 32 + kq * 8;
            bh[j] = *(const bf16x8*)(Bhs + off);
            bl[j] = *(const bf16x8*)(Bls + off);
        }
        #pragma unroll
        for (int i = 0; i < 4; i++)
            #pragma unroll
            for (int j = 0; j < 4; j++) {
                acc[i][j] = __builtin_amdgcn_mfma_f32_16x16x32_bf16(ah[i], bh[j], acc[i][j], 0, 0, 0);
                acc[i][j] = __builtin_amdgcn_mfma_f32_16x16x32_bf16(ah[i], bl[j], acc[i][j], 0, 0, 0);
                acc[i][j] = __builtin_amdgcn_mfma_f32_16x16x32_bf16(al[i], bh[j], acc[i][j], 0, 0, 0);
            }
        __syncthreads();
    }
    #pragma unroll
    for (int i = 0; i < 4; i++)
        #pragma unroll
        for (int j = 0; j < 4; j++) {
            int col = n0 + wn + j * 16 + l15;
            #pragma unroll
            for (int r = 0; r < 4; r++) {
                int row = m0 + wm + i * 16 + kq * 4 + r;
                C[(size_t)row * N + col] = acc[i][j][r];
            }
        }
}

// ------------- M[b,h,l] = max_s(q·k_s) - sum_s(q·k_s)/L  (sampled) ---------
__global__ __launch_bounds__(256) void calc_m(
    const float* __restrict__ Q, const float* __restrict__ Kb,
    const int* __restrict__ sidx, float* __restrict__ Mo, int U)
{
    int gid = blockIdx.x * 256 + threadIdx.x;   // b*H*L + h*L + l
    if (gid >= BB * HH * LL) return;
    int l = gid & (LL - 1);
    int h = (gid >> 11) & (HH - 1);
    int b = gid >> 14;
    const float* qr = Q + ((size_t)(b * LL + l) * DD + h * DKK);
    float q[DKK];
    #pragma unroll
    for (int d = 0; d < DKK; d++) q[d] = qr[d];
    float mx = -1e30f, sm = 0.f;
    for (int s = 0; s < U; s++) {
        int j = sidx[l * U + s];
        const float* kr = Kb + ((size_t)(b * LL + j) * DD + h * DKK);
        float dot = 0.f;
        #pragma unroll
        for (int d = 0; d < DKK; d++) dot += q[d] * kr[d];
        mx = fmaxf(mx, dot); sm += dot;
    }
    Mo[gid] = mx - sm * (1.0f / (float)LL);
}

// ------------- iterative top-40 per (b,h) row of M -------------------------
__global__ __launch_bounds__(256) void topk_k(
    const float* __restrict__ Mo, int* __restrict__ top, int U)
{
    __shared__ float sv[LL];
    __shared__ float rv[256];
    __shared__ int   ri[256];
    int bh = blockIdx.x, tid = threadIdx.x;
    for (int i = tid; i < LL; i += 256) sv[i] = Mo[(size_t)bh * LL + i];
    __syncthreads();
    for (int it = 0; it < U; it++) {
        float best = -1e38f; int bi = LL - 1;
        for (int i = tid; i < LL; i += 256) {
            float v = sv[i];
            if (v > best) { best = v; bi = i; }
        }
        rv[tid] = best; ri[tid] = bi; __syncthreads();
        for (int s = 128; s > 0; s >>= 1) {
            if (tid < s) {
                float vo = rv[tid + s]; int io = ri[tid + s];
                if (vo > rv[tid] || (vo == rv[tid] && io < ri[tid])) { rv[tid] = vo; ri[tid] = io; }
            }
            __syncthreads();
        }
        if (tid == 0) { top[bh * U + it] = ri[0]; sv[ri[0]] = -1e38f; }
        __syncthreads();
    }
}

// ------------- Vmean[b,h,d] (V bf16) ---------------------------------------
__global__ __launch_bounds__(64) void vmean_k(
    const __bf16* __restrict__ V, float* __restrict__ Vm)
{
    int bh = blockIdx.x, d = threadIdx.x;
    int b = bh >> 3, h = bh & 7;
    const __bf16* vp = V + ((size_t)b * LL * DD + h * DKK + d);
    float s = 0.f;
    for (int l = 0; l < LL; l++) s += (float)vp[(size_t)l * DD];
    Vm[bh * DKK + d] = s * (1.0f / (float)LL);
}

// ------------- fused: upd[row,:] = softmax(Q[top]·K^T/8) @ V ---------------
__global__ __launch_bounds__(256) void attn_fused(
    const float* __restrict__ Q, const float* __restrict__ Kb,
    const __bf16* __restrict__ V, const int* __restrict__ top,
    float* __restrict__ upd, int U)
{
    __shared__ float qs[DKK];
    __shared__ float p[LL];
    __shared__ float red[256];
    __shared__ float osum[4][DKK];
    int row = blockIdx.x;              // bh*U + u
    int u = row % U, bh = row / U;
    int h = bh & 7, b = bh >> 3;
    int tid = threadIdx.x;
    int tq = top[bh * U + u];
    if (tid < DKK) qs[tid] = Q[((size_t)(b * LL + tq) * DD + h * DKK) + tid];
    __syncthreads();
    float sc[8]; float mx = -1e30f;
    #pragma unroll
    for (int i = 0; i < 8; i++) {
        int l = tid + i * 256;
        const float4* kr = (const float4*)(Kb + ((size_t)(b * LL + l) * DD + h * DKK));
        float dot = 0.f;
        #pragma unroll
        for (int d4 = 0; d4 < 16; d4++) {
            float4 kv = kr[d4];
            dot += qs[d4 * 4 + 0] * kv.x + qs[d4 * 4 + 1] * kv.y
                 + qs[d4 * 4 + 2] * kv.z + qs[d4 * 4 + 3] * kv.w;
        }
        sc[i] = dot * 0.125f;
        mx = fmaxf(mx, sc[i]);
    }
    red[tid] = mx; __syncthreads();
    for (int s = 128; s > 0; s >>= 1) { if (tid < s) red[tid] = fmaxf(red[tid], red[tid + s]); __syncthreads(); }
    mx = red[0]; __syncthreads();
    float se = 0.f;
    #pragma unroll
    for (int i = 0; i < 8; i++) { sc[i] = __expf(sc[i] - mx); se += sc[i]; }
    red[tid] = se; __syncthreads();
    for (int s = 128; s > 0; s >>= 1) { if (tid < s) red[tid] += red[tid + s]; __syncthreads(); }
    float inv = 1.0f / red[0];
    #pragma unroll
    for (int i = 0; i < 8; i++) p[tid + i * 256] = sc[i] * inv;
    __syncthreads();
    // phase 2: upd[d] = sum_l p[l]*V[b,h,l,d]; 4 l-chunks of 512 in parallel
    int d = tid & 63, part = tid >> 6;
    const __bf16* vp = V + ((size_t)b * LL * DD + h * DKK + d);
    float acc = 0.f;
    int l0 = part * 512;
    for (int l = l0; l < l0 + 512; l++) acc += p[l] * (float)vp[(size_t)l * DD];
    osum[part][d] = acc;
    __syncthreads();
    if (tid < DKK)
        upd[(size_t)row * DKK + tid] = osum[0][tid] + osum[1][tid] + osum[2][tid] + osum[3][tid];
}

// ------------- ctx init (broadcast Vmean, bf16) + scatter ------------------
__global__ __launch_bounds__(256) void ctx_init(
    const float* __restrict__ Vm, __bf16* __restrict__ ctx)
{
    int idx = blockIdx.x * 256 + threadIdx.x;   // over B*L*512
    int c = idx & 511; int h = c >> 6, d = c & 63;
    int bl = idx >> 9; int b = bl >> 11;
    ctx[idx] = (__bf16)Vm[(b * HH + h) * DKK + d];
}
__global__ __launch_bounds__(256) void ctx_scatter(
    const float* __restrict__ upd, const int* __restrict__ top,
    __bf16* __restrict__ ctx, int U, int total)
{
    int idx = blockIdx.x * 256 + threadIdx.x;   // bh*U*64
    if (idx >= total) return;
    int d = idx & 63; int ru = idx >> 6;        // bh*U+u
    int bh = ru / U, u = ru % U;
    int b = bh >> 3, h = bh & 7;
    int l = top[bh * U + u];
    ctx[(((size_t)(b * LL + l)) << 9) + h * DKK + d] = (__bf16)upd[idx];
}

// ------------- LN1: x1 = LN(x + aout) -> bf16 ------------------------------
__global__ __launch_bounds__(256) void ln1_k(
    const float* __restrict__ x, const float* __restrict__ aout,
    const float* __restrict__ g, const float* __restrict__ bb,
    __bf16* __restrict__ x1h)
{
    __shared__ float red[256];
    int row = blockIdx.x, tid = threadIdx.x;
    size_t base = (size_t)row * DD;
    float h0 = x[base + tid] + aout[base + tid];
    float h1 = x[base + 256 + tid] + aout[base + 256 + tid];
    red[tid] = h0 + h1; __syncthreads();
    for (int s = 128; s > 0; s >>= 1) { if (tid < s) red[tid] += red[tid + s]; __syncthreads(); }
    float mean = red[0] * (1.0f / DD); __syncthreads();
    float d0 = h0 - mean, d1 = h1 - mean;
    red[tid] = d0 * d0 + d1 * d1; __syncthreads();
    for (int s = 128; s > 0; s >>= 1) { if (tid < s) red[tid] += red[tid + s]; __syncthreads(); }
    float rstd = rsqrtf(red[0] * (1.0f / DD) + 1e-5f);
    x1h[base + tid]       = (__bf16)(d0 * rstd * g[tid] + bb[tid]);
    x1h[base + 256 + tid] = (__bf16)(d1 * rstd * g[256 + tid] + bb[256 + tid]);
}

// ------------- LN2: out = LN(x1 + ffn2 + b2) -> fp32 -----------------------
__global__ __launch_bounds__(256) void ln2_k(
    const __bf16* __restrict__ x1h, const float* __restrict__ f2o,
    const float* __restrict__ c2b,
    const float* __restrict__ g, const float* __restrict__ bb,
    float* __restrict__ out)
{
    __shared__ float red[256];
    int row = blockIdx.x, tid = threadIdx.x;
    size_t base = (size_t)row * DD;
    float h0 = (float)x1h[base + tid] + f2o[base + tid] + c2b[tid];
    float h1 = (float)x1h[base + 256 + tid] + f2o[base + 256 + tid] + c2b[256 + tid];
    red[tid] = h0 + h1; __syncthreads();
    for (int s = 128; s > 0; s >>= 1) { if (tid < s) red[tid] += red[tid + s]; __syncthreads(); }
    float mean = red[0] * (1.0f / DD); __syncthreads();
    float d0 = h0 - mean, d1 = h1 - mean;
    red[tid] = d0 * d0 + d1 * d1; __syncthreads();
    for (int s = 128; s > 0; s >>= 1) { if (tid < s) red[tid] += red[tid + s]; __syncthreads(); }
    float rstd = rsqrtf(red[0] * (1.0f / DD) + 1e-5f);
    out[base + tid]       = d0 * rstd * g[tid] + bb[tid];
    out[base + 256 + tid] = d1 * rstd * g[256 + tid] + bb[256 + tid];
}

// ---------------------------------------------------------------------------
extern "C" void kernel_launch(void* const* d_in, const int* in_sizes, int n_in,
                              void* d_out, int out_size, void* d_ws, size_t ws_size,
                              hipStream_t stream)
{
    const float* x   = (const float*)d_in[0];
    const float* Wq  = (const float*)d_in[1];
    const float* Wk  = (const float*)d_in[2];
    const float* Wv  = (const float*)d_in[3];
    const float* Wo  = (const float*)d_in[4];
    const float* g1  = (const float*)d_in[5];
    const float* b1  = (const float*)d_in[6];
    const float* c1w = (const float*)d_in[7];
    const float* c1b = (const float*)d_in[8];
    const float* c2w = (const float*)d_in[9];
    const float* c2b = (const float*)d_in[10];
    const float* g2  = (const float*)d_in[11];
    const float* b2  = (const float*)d_in[12];
    const int* sidx  = (const int*)d_in[13];
    float* out       = (float*)d_out;

    const int U = in_sizes[13] / LL;            // 40
    const int M = BB * LL;                       // 8192

    // ---- workspace layout (~64 MB peak), lifetime-safe aliasing ----
    // [0,16M)   Q fp32        -> aout fp32 (after attn) -> f2o fp32 (after ln1)
    // [16,32M)  K fp32        -> ych[0:16M)   (K dead after attn_fused)
    // [32,40M)  V bf16 -> ctx bf16 -> ych[16:24M) (ctx dead after out-proj)
    // [40,48M)  xhi bf16      -> ych[24:32M)  (xhi dead after V-GEMM)
    // [48,56M)  xlo bf16      -> x1h bf16     (xlo dead after Q/K GEMMs)
    // [56,59M)  wb: WqThi,WqTlo,WkThi,WkTlo,WvT,WoT (6 x 0.5 MB bf16)
    // [59,61M)  c1w bf16   [61,63M) c2w bf16
    // [63M+)    Mo 256K, upd 320K, Vm 8K, top 8K
    char* ws = (char*)d_ws;
    const size_t MB = (size_t)1 << 20;
    float*  Q    = (float*)(ws + 0);
    float*  Kb   = (float*)(ws + 16 * MB);
    __bf16* V    = (__bf16*)(ws + 32 * MB);
    __bf16* xhi  = (__bf16*)(ws + 40 * MB);
    __bf16* xlo  = (__bf16*)(ws + 48 * MB);
    __bf16* wb   = (__bf16*)(ws + 56 * MB);
    __bf16* c1wb = (__bf16*)(ws + 59 * MB);
    __bf16* c2wb = (__bf16*)(ws + 61 * MB);
    float*  Mo   = (float*)(ws + 63 * MB);
    float*  upd  = (float*)(ws + 63 * MB + 256 * 1024);
    float*  Vm   = (float*)(ws + 63 * MB + 576 * 1024);
    int*    top  = (int*)  (ws + 63 * MB + 584 * 1024);
    float*  aout = Q;                               // alias: Q dead after attn_fused
    float*  f2o  = Q;                               // alias: aout dead after ln1
    __bf16* ctx  = V;                               // alias: V dead after attn_fused
    __bf16* ych  = (__bf16*)(ws + 16 * MB);         // 32 MB: K+V/ctx+xhi regions, all dead
    __bf16* x1h  = xlo;                             // alias: xlo dead after Q/K GEMMs
    (void)ws_size; (void)n_in; (void)out_size;

    const size_t SZ = (size_t)DD * DD;
    __bf16* WqThi = wb;          __bf16* WqTlo = wb + SZ;
    __bf16* WkThi = wb + 2 * SZ; __bf16* WkTlo = wb + 3 * SZ;
    __bf16* WvT   = wb + 4 * SZ; __bf16* WoT   = wb + 5 * SZ;

    // 1) weight prep + input split-cast
    prep_w<<<dim3(DD * DD / 256, 1, 4), 256, 0, stream>>>(Wq, Wk, Wv, Wo, wb);
    cast_cw<<<dim3(FF * DD / 256, 1, 2), 256, 0, stream>>>(c1w, c2w, c1wb, c2wb);
    split_cast_x<<<BB * LL * DD / 256, 256, 0, stream>>>(x, xhi, xlo);

    // 2) Q,K via split-precision MFMA (selection-faithful); V plain bf16
    dim3 gproj(DD / 128, M / 128);
    gemm_mfma_split<<<gproj, 256, 0, stream>>>(xhi, xlo, WqThi, WqTlo, Q,  M, DD, DD);
    gemm_mfma_split<<<gproj, 256, 0, stream>>>(xhi, xlo, WkThi, WkTlo, Kb, M, DD, DD);
    gemm_mfma<0, false, true ><<<gproj, 256, 0, stream>>>(xhi, WvT, nullptr, V, M, DD, DD);

    // 3) sampled sparsity measure M, top-k, V mean
    calc_m<<<BB * HH * LL / 256, 256, 0, stream>>>(Q, Kb, sidx, Mo, U);
    topk_k<<<BB * HH, 256, 0, stream>>>(Mo, top, U);
    vmean_k<<<BB * HH, 64, 0, stream>>>(V, Vm);

    // 4) fused sparse attention: softmax(Q_red K^T / 8) @ V -> upd (Q,K,V die)
    attn_fused<<<BB * HH * U, 256, 0, stream>>>(Q, Kb, V, top, upd, U);

    // 5) context assembly (ctx aliases V) + out-projection (aout aliases Q)
    ctx_init<<<M * DD / 256, 256, 0, stream>>>(Vm, ctx);
    int sc_total = BB * HH * U * DKK;
    ctx_scatter<<<(sc_total + 255) / 256, 256, 0, stream>>>(upd, top, ctx, U, sc_total);
    gemm_mfma<0, false, false><<<gproj, 256, 0, stream>>>(ctx, WoT, nullptr, aout, M, DD, DD);

    // 6) LN1 -> x1h bf16 (aliases xlo)
    ln1_k<<<M, 256, 0, stream>>>(x, aout, g1, b1, x1h);

    // 7) FFN (un-chunked): gelu(x1 @ c1w^T + c1b) -> ych bf16; ych @ c2w^T -> f2o
    gemm_mfma<1, true,  true ><<<dim3(FF / 128, M / 128), 256, 0, stream>>>(x1h, c1wb, c1b, ych, M, FF, DD);
    gemm_mfma<0, false, false><<<dim3(DD / 128, M / 128), 256, 0, stream>>>(ych, c2wb, nullptr, f2o, M, DD, FF);

    // 8) LN2 -> fp32 output
    ln2_k<<<M, 256, 0, stream>>>(x1h, f2o, c2b, g2, b2, out);
}

// Round 6
// 555.190 us; speedup vs baseline: 3.0674x; 1.1691x over previous
//
#include <hip/hip_runtime.h>
#include <hip/hip_bf16.h>

// Problem constants (B=4, L=2048, D=512, H=8, DK=64, FF=2048, U=40)
#define BB 4
#define LL 2048
#define DD 512
#define HH 8
#define DKK 64
#define FF 2048

typedef __bf16  bf16x8  __attribute__((ext_vector_type(8)));
typedef float   floatx4 __attribute__((ext_vector_type(4)));

// async 16B global->LDS copy (global_load_lds_dwordx4)
__device__ __forceinline__ void async_cp16(const void* g, void* l) {
    __builtin_amdgcn_global_load_lds(
        (const __attribute__((address_space(1))) unsigned int*)g,
        (__attribute__((address_space(3))) unsigned int*)l,
        16, 0, 0);
}

// ---------- prep: transpose 512x512 fp32 -> bf16 (N,K); Wq/Wk also lo-part ----
__global__ __launch_bounds__(256) void prep_w(
    const float* __restrict__ Wq, const float* __restrict__ Wk,
    const float* __restrict__ Wv, const float* __restrict__ Wo,
    __bf16* __restrict__ wb)
{
    const size_t SZ = (size_t)DD * DD;
    int z = blockIdx.z;
    const float* s = (z == 0) ? Wq : (z == 1) ? Wk : (z == 2) ? Wv : Wo;
    __bf16* hi; __bf16* lo = nullptr;
    if (z == 0)      { hi = wb;          lo = wb + SZ; }
    else if (z == 1) { hi = wb + 2 * SZ; lo = wb + 3 * SZ; }
    else if (z == 2) { hi = wb + 4 * SZ; }
    else             { hi = wb + 5 * SZ; }
    int idx = blockIdx.x * 256 + threadIdx.x;   // 0..512*512-1
    int k = idx >> 9, n = idx & 511;
    float v = s[idx];
    __bf16 h = (__bf16)v;
    hi[(size_t)n * DD + k] = h;
    if (lo) lo[(size_t)n * DD + k] = (__bf16)(v - (float)h);
}

// ---------- cast conv weights fp32 (N,K) -> bf16 -----------------------------
__global__ __launch_bounds__(256) void cast_cw(
    const float* __restrict__ c1w, const float* __restrict__ c2w,
    __bf16* __restrict__ d1, __bf16* __restrict__ d2)
{
    const float* s = blockIdx.z ? c2w : c1w;
    __bf16* d = blockIdx.z ? d2 : d1;
    int idx = blockIdx.x * 256 + threadIdx.x;   // 0..FF*DD-1
    d[idx] = (__bf16)s[idx];
}

// ---------- split-cast x fp32 -> bf16 hi + lo --------------------------------
__global__ __launch_bounds__(256) void split_cast_x(
    const float* __restrict__ x, __bf16* __restrict__ xhi, __bf16* __restrict__ xlo)
{
    int idx = blockIdx.x * 256 + threadIdx.x;
    float v = x[idx];
    __bf16 h = (__bf16)v;
    xhi[idx] = h;
    xlo[idx] = (__bf16)(v - (float)h);
}

// ---------- MFMA GEMM: C[M,N] = act(A[M,K] @ B[N,K]^T + bias) ----------------
template<int ACT, bool BIAS, bool OUT_BF16>
__global__ __launch_bounds__(256) void gemm_mfma(
    const __bf16* __restrict__ A, const __bf16* __restrict__ B,
    const float* __restrict__ bias, void* __restrict__ Cv,
    int M, int N, int K)
{
    __shared__ __bf16 As[128 * 32];
    __shared__ __bf16 Bs[128 * 32];
    const int tid = threadIdx.x;
    const int wave = tid >> 6, lane = tid & 63;
    const int m0 = blockIdx.y * 128, n0 = blockIdx.x * 128;
    const int wm = (wave >> 1) * 64, wn = (wave & 1) * 64;
    const int l15 = lane & 15, kq = lane >> 4;

    floatx4 acc[4][4] = {};

    for (int k0 = 0; k0 < K; k0 += 32) {
        #pragma unroll
        for (int p = 0; p < 2; p++) {
            int c = p * 256 + tid;              // 16B chunk id 0..511
            int row = c >> 2, col = (c & 3) * 8;
            async_cp16(A + (size_t)(m0 + row) * K + k0 + col, As + c * 8);
            async_cp16(B + (size_t)(n0 + row) * K + k0 + col, Bs + c * 8);
        }
        __syncthreads();
        bf16x8 af[4], bfr[4];
        #pragma unroll
        for (int i = 0; i < 4; i++)
            af[i] = *(const bf16x8*)(As + (wm + i * 16 + l15) * 32 + kq * 8);
        #pragma unroll
        for (int j = 0; j < 4; j++)
            bfr[j] = *(const bf16x8*)(Bs + (wn + j * 16 + l15) * 32 + kq * 8);
        #pragma unroll
        for (int i = 0; i < 4; i++)
            #pragma unroll
            for (int j = 0; j < 4; j++)
                acc[i][j] = __builtin_amdgcn_mfma_f32_16x16x32_bf16(af[i], bfr[j], acc[i][j], 0, 0, 0);
        __syncthreads();
    }
    #pragma unroll
    for (int i = 0; i < 4; i++) {
        #pragma unroll
        for (int j = 0; j < 4; j++) {
            int col = n0 + wn + j * 16 + l15;
            float bv = BIAS ? bias[col] : 0.0f;
            #pragma unroll
            for (int r = 0; r < 4; r++) {
                int row = m0 + wm + i * 16 + kq * 4 + r;
                float v = acc[i][j][r] + bv;
                if (ACT == 1) v = 0.5f * v * (1.0f + erff(v * 0.70710678118654752f));
                if (OUT_BF16) ((__bf16*)Cv)[(size_t)row * N + col] = (__bf16)v;
                else          ((float*)Cv)[(size_t)row * N + col] = v;
            }
        }
    }
}

// ---------- split-precision MFMA GEMM (near-fp32): C = (Ah+Al)(Bh+Bl)^T ------
__global__ __launch_bounds__(256) void gemm_mfma_split(
    const __bf16* __restrict__ Ah, const __bf16* __restrict__ Al,
    const __bf16* __restrict__ Bh, const __bf16* __restrict__ Bl,
    float* __restrict__ C, int M, int N, int K)
{
    __shared__ __bf16 Ahs[128 * 32];
    __shared__ __bf16 Als[128 * 32];
    __shared__ __bf16 Bhs[128 * 32];
    __shared__ __bf16 Bls[128 * 32];
    const int tid = threadIdx.x;
    const int wave = tid >> 6, lane = tid & 63;
    const int m0 = blockIdx.y * 128, n0 = blockIdx.x * 128;
    const int wm = (wave >> 1) * 64, wn = (wave & 1) * 64;
    const int l15 = lane & 15, kq = lane >> 4;

    floatx4 acc[4][4] = {};

    for (int k0 = 0; k0 < K; k0 += 32) {
        #pragma unroll
        for (int p = 0; p < 2; p++) {
            int c = p * 256 + tid;
            int row = c >> 2, col = (c & 3) * 8;
            size_t goA = (size_t)(m0 + row) * K + k0 + col;
            size_t goB = (size_t)(n0 + row) * K + k0 + col;
            async_cp16(Ah + goA, Ahs + c * 8);
            async_cp16(Al + goA, Als + c * 8);
            async_cp16(Bh + goB, Bhs + c * 8);
            async_cp16(Bl + goB, Bls + c * 8);
        }
        __syncthreads();
        bf16x8 ah[4], al[4], bh[4], bl[4];
        #pragma unroll
        for (int i = 0; i < 4; i++) {
            int off = (wm + i * 16 + l15) * 32 + kq * 8;
            ah[i] = *(const bf16x8*)(Ahs + off);
            al[i] = *(const bf16x8*)(Als + off);
        }
        #pragma unroll
        for (int j = 0; j < 4; j++) {
            int off = (wn + j * 16 + l15) * 32 + kq * 8;
            bh[j] = *(const bf16x8*)(Bhs + off);
            bl[j] = *(const bf16x8*)(Bls + off);
        }
        #pragma unroll
        for (int i = 0; i < 4; i++)
            #pragma unroll
            for (int j = 0; j < 4; j++) {
                acc[i][j] = __builtin_amdgcn_mfma_f32_16x16x32_bf16(ah[i], bh[j], acc[i][j], 0, 0, 0);
                acc[i][j] = __builtin_amdgcn_mfma_f32_16x16x32_bf16(ah[i], bl[j], acc[i][j], 0, 0, 0);
                acc[i][j] = __builtin_amdgcn_mfma_f32_16x16x32_bf16(al[i], bh[j], acc[i][j], 0, 0, 0);
            }
        __syncthreads();
    }
    #pragma unroll
    for (int i = 0; i < 4; i++)
        #pragma unroll
        for (int j = 0; j < 4; j++) {
            int col = n0 + wn + j * 16 + l15;
            #pragma unroll
            for (int r = 0; r < 4; r++) {
                int row = m0 + wm + i * 16 + kq * 4 + r;
                C[(size_t)row * N + col] = acc[i][j][r];
            }
        }
}

// ------------- M[b,h,l] = max_s(q·k_s) - sum_s(q·k_s)/L  (sampled) ---------
__global__ __launch_bounds__(256) void calc_m(
    const float* __restrict__ Q, const float* __restrict__ Kb,
    const int* __restrict__ sidx, float* __restrict__ Mo, int U)
{
    int gid = blockIdx.x * 256 + threadIdx.x;   // b*H*L + h*L + l
    if (gid >= BB * HH * LL) return;
    int l = gid & (LL - 1);
    int h = (gid >> 11) & (HH - 1);
    int b = gid >> 14;
    const float* qr = Q + ((size_t)(b * LL + l) * DD + h * DKK);
    float q[DKK];
    #pragma unroll
    for (int d = 0; d < DKK; d++) q[d] = qr[d];
    float mx = -1e30f, sm = 0.f;
    for (int s = 0; s < U; s++) {
        int j = sidx[l * U + s];
        const float* kr = Kb + ((size_t)(b * LL + j) * DD + h * DKK);
        float dot = 0.f;
        #pragma unroll
        for (int d = 0; d < DKK; d++) dot += q[d] * kr[d];
        mx = fmaxf(mx, dot); sm += dot;
    }
    Mo[gid] = mx - sm * (1.0f / (float)LL);
}

// ------------- iterative top-40 per (b,h) row of M -------------------------
__global__ __launch_bounds__(256) void topk_k(
    const float* __restrict__ Mo, int* __restrict__ top, int U)
{
    __shared__ float sv[LL];
    __shared__ float rv[256];
    __shared__ int   ri[256];
    int bh = blockIdx.x, tid = threadIdx.x;
    for (int i = tid; i < LL; i += 256) sv[i] = Mo[(size_t)bh * LL + i];
    __syncthreads();
    for (int it = 0; it < U; it++) {
        float best = -1e38f; int bi = LL - 1;
        for (int i = tid; i < LL; i += 256) {
            float v = sv[i];
            if (v > best) { best = v; bi = i; }
        }
        rv[tid] = best; ri[tid] = bi; __syncthreads();
        for (int s = 128; s > 0; s >>= 1) {
            if (tid < s) {
                float vo = rv[tid + s]; int io = ri[tid + s];
                if (vo > rv[tid] || (vo == rv[tid] && io < ri[tid])) { rv[tid] = vo; ri[tid] = io; }
            }
            __syncthreads();
        }
        if (tid == 0) { top[bh * U + it] = ri[0]; sv[ri[0]] = -1e38f; }
        __syncthreads();
    }
}

// ------------- Vmean[b,h,d] (V bf16), 256 threads/block --------------------
__global__ __launch_bounds__(256) void vmean_k(
    const __bf16* __restrict__ V, float* __restrict__ Vm)
{
    __shared__ float osum[4][DKK];
    int bh = blockIdx.x;
    int b = bh >> 3, h = bh & 7;
    int tid = threadIdx.x, d = tid & 63, part = tid >> 6;
    const __bf16* vp = V + ((size_t)(b * LL + part * 512) * DD + h * DKK + d);
    float s = 0.f;
    for (int i = 0; i < 512; i++) s += (float)vp[(size_t)i * DD];
    osum[part][d] = s;
    __syncthreads();
    if (tid < DKK)
        Vm[bh * DKK + tid] = (osum[0][tid] + osum[1][tid] + osum[2][tid] + osum[3][tid]) * (1.0f / (float)LL);
}

// ------------- gather Q[top] -> qred[32][48][64] bf16, scaled by 1/8 -------
__global__ __launch_bounds__(256) void gather_qred(
    const float* __restrict__ Q, const int* __restrict__ top,
    __bf16* __restrict__ qred, int U)
{
    int bh = blockIdx.y;
    int b = bh >> 3, h = bh & 7;
    int e = blockIdx.x * 256 + threadIdx.x;   // 0..48*64-1
    int u = e >> 6, d = e & 63;
    float v = 0.f;
    if (u < U) {
        int l = top[bh * U + u];
        v = Q[((size_t)(b * LL + l) * DD + h * DKK) + d] * 0.125f;
    }
    qred[(size_t)bh * 48 * DKK + e] = (__bf16)v;
}

// ------------- batched S[bh][48][2048] = qred[bh] @ K[bh]^T (MFMA) ---------
__global__ __launch_bounds__(256) void gemm_s(
    const __bf16* __restrict__ qred, const float* __restrict__ Kb,
    float* __restrict__ S)
{
    __shared__ __bf16 Qs[2 * 48 * 32];    // 2 panels of BK=32
    __shared__ __bf16 Ks[2 * 128 * 32];
    int bh = blockIdx.y, nc = blockIdx.x;
    int b = bh >> 3, h = bh & 7, l0 = nc * 128;
    int tid = threadIdx.x;
    // stage Q: 48x64 bf16 = 1536 uints; panel p = k>>5
    const unsigned int* qsrc = (const unsigned int*)(qred + (size_t)bh * 48 * DKK);
    unsigned int* qdst = (unsigned int*)Qs;
    #pragma unroll
    for (int t = 0; t < 6; t++) {
        int ui = tid + t * 256;            // 0..1535
        int u = ui >> 5, kp = ui & 31;     // kp = uint index within row (2 bf16 each)
        int p = kp >> 4, kl2 = kp & 15;
        qdst[p * 768 + u * 16 + kl2] = qsrc[ui];
    }
    // stage K: 128 rows x 64 k fp32 -> bf16; 2048 float4
    #pragma unroll
    for (int t = 0; t < 8; t++) {
        int fi = tid + t * 256;            // 0..2047
        int row = fi >> 4, k4 = fi & 15;   // k = k4*4
        int p = k4 >> 3, kl = (k4 & 7) * 4;
        float4 kv = *(const float4*)(Kb + ((size_t)(b * LL + l0 + row) * DD + h * DKK + k4 * 4));
        __bf16* dst = Ks + p * 128 * 32 + row * 32 + kl;
        dst[0] = (__bf16)kv.x; dst[1] = (__bf16)kv.y;
        dst[2] = (__bf16)kv.z; dst[3] = (__bf16)kv.w;
    }
    __syncthreads();
    int wave = tid >> 6, lane = tid & 63, l15 = lane & 15, kq = lane >> 4;
    floatx4 acc[3][2] = {};
    #pragma unroll
    for (int p = 0; p < 2; p++) {
        bf16x8 bq[2];
        #pragma unroll
        for (int j = 0; j < 2; j++)
            bq[j] = *(const bf16x8*)(Ks + p * 4096 + (wave * 32 + j * 16 + l15) * 32 + kq * 8);
        #pragma unroll
        for (int i = 0; i < 3; i++) {
            bf16x8 aq = *(const bf16x8*)(Qs + p * 1536 + (i * 16 + l15) * 32 + kq * 8);
            #pragma unroll
            for (int j = 0; j < 2; j++)
                acc[i][j] = __builtin_amdgcn_mfma_f32_16x16x32_bf16(aq, bq[j], acc[i][j], 0, 0, 0);
        }
    }
    #pragma unroll
    for (int i = 0; i < 3; i++)
        #pragma unroll
        for (int j = 0; j < 2; j++) {
            int col = l0 + wave * 32 + j * 16 + l15;
            #pragma unroll
            for (int r = 0; r < 4; r++) {
                int row = i * 16 + kq * 4 + r;
                S[((size_t)bh * 48 + row) * LL + col] = acc[i][j][r];
            }
        }
}

// ------------- row softmax, in-place: S row fp32 -> P row bf16 -------------
__global__ __launch_bounds__(256) void softmax_p(float* __restrict__ S, int U)
{
    __shared__ float red[256];
    int row = blockIdx.x;              // 32*U rows
    int bh = row / U, u = row % U;
    float* sr = S + ((size_t)bh * 48 + u) * LL;
    int tid = threadIdx.x;
    float sc[8]; float mx = -1e30f;
    #pragma unroll
    for (int i = 0; i < 8; i++) { sc[i] = sr[tid + i * 256]; mx = fmaxf(mx, sc[i]); }
    red[tid] = mx; __syncthreads();
    for (int s = 128; s > 0; s >>= 1) { if (tid < s) red[tid] = fmaxf(red[tid], red[tid + s]); __syncthreads(); }
    mx = red[0]; __syncthreads();
    float se = 0.f;
    #pragma unroll
    for (int i = 0; i < 8; i++) { sc[i] = __expf(sc[i] - mx); se += sc[i]; }
    red[tid] = se; __syncthreads();
    for (int s = 128; s > 0; s >>= 1) { if (tid < s) red[tid] += red[tid + s]; __syncthreads(); }
    float inv = 1.0f / red[0];
    // all reads of sr completed before the reductions' barriers -> safe overwrite
    __bf16* pr = (__bf16*)sr;
    #pragma unroll
    for (int i = 0; i < 8; i++) pr[tid + i * 256] = (__bf16)(sc[i] * inv);
}

// ------------- upd[bh][u][d] = sum_l P[u][l] * V[b,h,l,d], 4 u per block ----
__global__ __launch_bounds__(256) void pv_k(
    const float* __restrict__ S, const __bf16* __restrict__ V,
    float* __restrict__ upd, int U)
{
    __shared__ __bf16 pls[4 * LL];      // 16 KB
    __shared__ float osum[4][4][DKK];   // part, u', d
    int bh = blockIdx.y, uc = blockIdx.x;
    int b = bh >> 3, h = bh & 7, tid = threadIdx.x;
    // stage P rows (bf16 in-place at S row starts; row stride = LL fp32)
    #pragma unroll
    for (int t = 0; t < 16; t++) {
        int ui = tid + t * 256;          // 0..4095 uints
        int up = ui >> 10, lw = ui & 1023;
        const unsigned int* src = (const unsigned int*)(S + ((size_t)bh * 48 + uc * 4 + up) * LL);
        ((unsigned int*)pls)[up * 1024 + lw] = src[lw];
    }
    __syncthreads();
    int d = tid & 63, part = tid >> 6;
    float a0 = 0.f, a1 = 0.f, a2 = 0.f, a3 = 0.f;
    const __bf16* vp = V + ((size_t)(b * LL + part * 512) * DD + h * DKK + d);
    int lbase = part * 512;
    for (int i = 0; i < 512; i++) {
        float v = (float)vp[(size_t)i * DD];
        int l = lbase + i;
        a0 += (float)pls[l] * v;
        a1 += (float)pls[LL + l] * v;
        a2 += (float)pls[2 * LL + l] * v;
        a3 += (float)pls[3 * LL + l] * v;
    }
    osum[part][0][d] = a0; osum[part][1][d] = a1;
    osum[part][2][d] = a2; osum[part][3][d] = a3;
    __syncthreads();
    int u2 = tid >> 6;
    float s = osum[0][u2][d] + osum[1][u2][d] + osum[2][u2][d] + osum[3][u2][d];
    upd[((size_t)bh * U + uc * 4 + u2) * DKK + d] = s;
}

// ------------- ctx init (broadcast Vmean, bf16) + scatter ------------------
__global__ __launch_bounds__(256) void ctx_init(
    const float* __restrict__ Vm, __bf16* __restrict__ ctx)
{
    int idx = blockIdx.x * 256 + threadIdx.x;   // over B*L*512
    int c = idx & 511; int h = c >> 6, d = c & 63;
    int bl = idx >> 9; int b = bl >> 11;
    ctx[idx] = (__bf16)Vm[(b * HH + h) * DKK + d];
}
__global__ __launch_bounds__(256) void ctx_scatter(
    const float* __restrict__ upd, const int* __restrict__ top,
    __bf16* __restrict__ ctx, int U, int total)
{
    int idx = blockIdx.x * 256 + threadIdx.x;   // bh*U*64
    if (idx >= total) return;
    int d = idx & 63; int ru = idx >> 6;        // bh*U+u
    int bh = ru / U, u = ru % U;
    int b = bh >> 3, h = bh & 7;
    int l = top[bh * U + u];
    ctx[(((size_t)(b * LL + l)) << 9) + h * DKK + d] = (__bf16)upd[idx];
}

// ------------- LN1: x1 = LN(x + aout) -> bf16 ------------------------------
__global__ __launch_bounds__(256) void ln1_k(
    const float* __restrict__ x, const float* __restrict__ aout,
    const float* __restrict__ g, const float* __restrict__ bb,
    __bf16* __restrict__ x1h)
{
    __shared__ float red[256];
    int row = blockIdx.x, tid = threadIdx.x;
    size_t base = (size_t)row * DD;
    float h0 = x[base + tid] + aout[base + tid];
    float h1 = x[base + 256 + tid] + aout[base + 256 + tid];
    red[tid] = h0 + h1; __syncthreads();
    for (int s = 128; s > 0; s >>= 1) { if (tid < s) red[tid] += red[tid + s]; __syncthreads(); }
    float mean = red[0] * (1.0f / DD); __syncthreads();
    float d0 = h0 - mean, d1 = h1 - mean;
    red[tid] = d0 * d0 + d1 * d1; __syncthreads();
    for (int s = 128; s > 0; s >>= 1) { if (tid < s) red[tid] += red[tid + s]; __syncthreads(); }
    float rstd = rsqrtf(red[0] * (1.0f / DD) + 1e-5f);
    x1h[base + tid]       = (__bf16)(d0 * rstd * g[tid] + bb[tid]);
    x1h[base + 256 + tid] = (__bf16)(d1 * rstd * g[256 + tid] + bb[256 + tid]);
}

// ------------- LN2: out = LN(x1 + ffn2 + b2) -> fp32 -----------------------
__global__ __launch_bounds__(256) void ln2_k(
    const __bf16* __restrict__ x1h, const float* __restrict__ f2o,
    const float* __restrict__ c2b,
    const float* __restrict__ g, const float* __restrict__ bb,
    float* __restrict__ out)
{
    __shared__ float red[256];
    int row = blockIdx.x, tid = threadIdx.x;
    size_t base = (size_t)row * DD;
    float h0 = (float)x1h[base + tid] + f2o[base + tid] + c2b[tid];
    float h1 = (float)x1h[base + 256 + tid] + f2o[base + 256 + tid] + c2b[256 + tid];
    red[tid] = h0 + h1; __syncthreads();
    for (int s = 128; s > 0; s >>= 1) { if (tid < s) red[tid] += red[tid + s]; __syncthreads(); }
    float mean = red[0] * (1.0f / DD); __syncthreads();
    float d0 = h0 - mean, d1 = h1 - mean;
    red[tid] = d0 * d0 + d1 * d1; __syncthreads();
    for (int s = 128; s > 0; s >>= 1) { if (tid < s) red[tid] += red[tid + s]; __syncthreads(); }
    float rstd = rsqrtf(red[0] * (1.0f / DD) + 1e-5f);
    out[base + tid]       = d0 * rstd * g[tid] + bb[tid];
    out[base + 256 + tid] = d1 * rstd * g[256 + tid] + bb[256 + tid];
}

// ---------------------------------------------------------------------------
extern "C" void kernel_launch(void* const* d_in, const int* in_sizes, int n_in,
                              void* d_out, int out_size, void* d_ws, size_t ws_size,
                              hipStream_t stream)
{
    const float* x   = (const float*)d_in[0];
    const float* Wq  = (const float*)d_in[1];
    const float* Wk  = (const float*)d_in[2];
    const float* Wv  = (const float*)d_in[3];
    const float* Wo  = (const float*)d_in[4];
    const float* g1  = (const float*)d_in[5];
    const float* b1  = (const float*)d_in[6];
    const float* c1w = (const float*)d_in[7];
    const float* c1b = (const float*)d_in[8];
    const float* c2w = (const float*)d_in[9];
    const float* c2b = (const float*)d_in[10];
    const float* g2  = (const float*)d_in[11];
    const float* b2  = (const float*)d_in[12];
    const int* sidx  = (const int*)d_in[13];
    float* out       = (float*)d_out;

    const int U = in_sizes[13] / LL;            // 40
    const int M = BB * LL;                       // 8192

    // ---- workspace layout (~64 MB), lifetime-safe aliasing ----
    // [0,16M)   Q fp32        -> aout fp32 (after PV) -> f2o fp32 (after ln1)
    // [16,32M)  K fp32        -> ych[0:16M)  (K dead after gemm_s)
    // [32,40M)  V bf16 -> ctx bf16 -> ych[16:24M)
    // [40,48M)  xhi bf16 ─┐   S fp32 [40, 52.6M) during attention;
    // [48,56M)  xlo bf16 ─┘   x1h bf16 at [48,56) from ln1 on (S/P dead)
    // [56,59M)  wb (6 x 512KB bf16)   [59,61M) c1w bf16   [61,63M) c2w bf16
    // [63M+)    Mo 256K | upd 320K | Vm 8K | top 8K | qred 192K
    char* ws = (char*)d_ws;
    const size_t MB = (size_t)1 << 20;
    float*  Q    = (float*)(ws + 0);
    float*  Kb   = (float*)(ws + 16 * MB);
    __bf16* V    = (__bf16*)(ws + 32 * MB);
    __bf16* xhi  = (__bf16*)(ws + 40 * MB);
    __bf16* xlo  = (__bf16*)(ws + 48 * MB);
    float*  S    = (float*)(ws + 40 * MB);          // 32*48*2048*4 = 12.6 MB
    __bf16* wb   = (__bf16*)(ws + 56 * MB);
    __bf16* c1wb = (__bf16*)(ws + 59 * MB);
    __bf16* c2wb = (__bf16*)(ws + 61 * MB);
    float*  Mo   = (float*)(ws + 63 * MB);
    float*  upd  = (float*)(ws + 63 * MB + 256 * 1024);
    float*  Vm   = (float*)(ws + 63 * MB + 576 * 1024);
    int*    top  = (int*)  (ws + 63 * MB + 584 * 1024);
    __bf16* qred = (__bf16*)(ws + 63 * MB + 592 * 1024);  // 32*48*64*2 = 192K
    float*  aout = Q;                               // alias: Q dead after gather/gemm_s
    float*  f2o  = Q;                               // alias: aout dead after ln1
    __bf16* ctx  = V;                               // alias: V dead after pv_k
    __bf16* ych  = (__bf16*)(ws + 16 * MB);         // FFN intermediate (32 MB region)
    __bf16* x1h  = xlo;                             // alias: S/P dead by ln1
    (void)ws_size; (void)n_in; (void)out_size;

    const size_t SZ = (size_t)DD * DD;
    __bf16* WqThi = wb;          __bf16* WqTlo = wb + SZ;
    __bf16* WkThi = wb + 2 * SZ; __bf16* WkTlo = wb + 3 * SZ;
    __bf16* WvT   = wb + 4 * SZ; __bf16* WoT   = wb + 5 * SZ;

    // 1) weight prep + input split-cast
    prep_w<<<dim3(DD * DD / 256, 1, 4), 256, 0, stream>>>(Wq, Wk, Wv, Wo, wb);
    cast_cw<<<dim3(FF * DD / 256, 1, 2), 256, 0, stream>>>(c1w, c2w, c1wb, c2wb);
    split_cast_x<<<BB * LL * DD / 256, 256, 0, stream>>>(x, xhi, xlo);

    // 2) Q,K via split-precision MFMA (selection-faithful); V plain bf16
    dim3 gproj(DD / 128, M / 128);
    gemm_mfma_split<<<gproj, 256, 0, stream>>>(xhi, xlo, WqThi, WqTlo, Q,  M, DD, DD);
    gemm_mfma_split<<<gproj, 256, 0, stream>>>(xhi, xlo, WkThi, WkTlo, Kb, M, DD, DD);
    gemm_mfma<0, false, true ><<<gproj, 256, 0, stream>>>(xhi, WvT, nullptr, V, M, DD, DD);

    // 3) sampled sparsity measure M, top-k, V mean
    calc_m<<<BB * HH * LL / 256, 256, 0, stream>>>(Q, Kb, sidx, Mo, U);
    topk_k<<<BB * HH, 256, 0, stream>>>(Mo, top, U);
    vmean_k<<<BB * HH, 256, 0, stream>>>(V, Vm);

    // 4) attention: gather -> batched MFMA S -> softmax(in-place bf16 P) -> PV
    gather_qred<<<dim3(48 * DKK / 256, BB * HH), 256, 0, stream>>>(Q, top, qred, U);
    gemm_s<<<dim3(LL / 128, BB * HH), 256, 0, stream>>>(qred, Kb, S);
    softmax_p<<<BB * HH * U, 256, 0, stream>>>(S, U);
    pv_k<<<dim3(U / 4, BB * HH), 256, 0, stream>>>(S, V, upd, U);

    // 5) context assembly (ctx aliases V) + out-projection (aout aliases Q)
    ctx_init<<<M * DD / 256, 256, 0, stream>>>(Vm, ctx);
    int sc_total = BB * HH * U * DKK;
    ctx_scatter<<<(sc_total + 255) / 256, 256, 0, stream>>>(upd, top, ctx, U, sc_total);
    gemm_mfma<0, false, false><<<gproj, 256, 0, stream>>>(ctx, WoT, nullptr, aout, M, DD, DD);

    // 6) LN1 -> x1h bf16 (aliases xlo; S/P dead)
    ln1_k<<<M, 256, 0, stream>>>(x, aout, g1, b1, x1h);

    // 7) FFN: gelu(x1 @ c1w^T + c1b) -> ych bf16; ych @ c2w^T -> f2o
    gemm_mfma<1, true,  true ><<<dim3(FF / 128, M / 128), 256, 0, stream>>>(x1h, c1wb, c1b, ych, M, FF, DD);
    gemm_mfma<0, false, false><<<dim3(DD / 128, M / 128), 256, 0, stream>>>(ych, c2wb, nullptr, f2o, M, DD, FF);

    // 8) LN2 -> fp32 output
    ln2_k<<<M, 256, 0, stream>>>(x1h, f2o, c2b, g2, b2, out);
}